// Round 7
// baseline (683.716 us; speedup 1.0000x reference)
//
#include <hip/hip_runtime.h>

// ---------------------------------------------------------------------------
// Llama4TextExperts: per-expert  out = (up * silu(gate)) @ W2
// E=8, T=8192 (1024/expert), H=2048, I=4096, fp32 in/out, bf16 MFMA compute.
// R7: 128x128x64 tile, 4 waves, 64KB LDS -> 2 blocks/CU (inter-block stall
//     overlap). B fused fp32 path kept (quad-ownership f4 loads, conflict-
//     free writes) + pi-permuted B-fragment reads (2-way, free) with the
//     permutation absorbed in the epilogue column index.
// ---------------------------------------------------------------------------

#define E_   8
#define H_   2048
#define I_   4096
#define T_   8192
#define TPE  1024

typedef __bf16 bf16x8 __attribute__((ext_vector_type(8)));
typedef float  f32x4  __attribute__((ext_vector_type(4)));

__device__ __forceinline__ unsigned short f2bf(float f) {
  union { float f; unsigned int u; } v; v.f = f;
  unsigned int u = v.u;
  u += 0x7FFFu + ((u >> 16) & 1u);   // RNE
  return (unsigned short)(u >> 16);
}

__device__ __forceinline__ void async16(const void* g, void* l) {
  __builtin_amdgcn_global_load_lds(
      (__attribute__((address_space(1))) void*)(g),
      (__attribute__((address_space(3))) void*)(l), 16, 0, 0);
}

#define SB0()      __builtin_amdgcn_sched_barrier(0)
#define BAR()      __builtin_amdgcn_s_barrier()
#define WAITLGKM() asm volatile("s_waitcnt lgkmcnt(0)" ::: "memory")
#define WAITVM(n)  asm volatile("s_waitcnt vmcnt(" #n ")" ::: "memory")

// ---------------------------------------------------------------------------
__global__ void convert_bf16(const float* __restrict__ src,
                             unsigned short* __restrict__ dst, long n) {
  long i = ((long)blockIdx.x * blockDim.x + threadIdx.x) * 4;
  const long stride = (long)gridDim.x * blockDim.x * 4;
  for (; i < n; i += stride) {
    const float4 v = *(const float4*)&src[i];
    ushort4 o;
    o.x = f2bf(v.x); o.y = f2bf(v.y); o.z = f2bf(v.z); o.w = f2bf(v.w);
    *(ushort4*)&dst[i] = o;
  }
}

// ---------------------------------------------------------------------------
// 128x128x64 4-phase GEMM, 4 waves (2Mx2N), wave tile 64x64.
// LDS 64KB: A[2][128 rows][64] bf16 + B[2][128 rows][64] bf16 -> 2 blocks/CU.
// A: bf16 (M,K) via global_load_lds, linear dest, source pre-swizzled so
//    LDS slot s of row r holds k-octet s^(r&7).
// B: fp32 (K,N); thread (quad=tid&31, ko=tid>>5) loads 8 float4 along N
//    (4 contiguous cols), transposes, writes 4x ds_write_b128 at
//    slot = ko ^ (quad&7)   [8 distinct slots per 8-lane group: conflict-free]
// B-frag read: lane lr reads storage row nbase + pi(lr), pi = 2-bit halves
//    swapped; key (st>>2)&7 spans 4 slots x2 lanes per 8-lane group (2-way,
//    free). Epilogue compensates: output col j -> actual col nbase + pi(j).
// vmcnt ledger (per-thread FIFO, per tile) — identical counts to R5:
//   P1 issues A q0(t+2) [2] | P2: vmcnt(4) -> WRITEB B(t+1) [4 ds_write],
//   lgkm0, LOADB B(t+2) [8 f4] | P3 issues A q1(t+2) [2], vmcnt(12).
// A-stage rows {0-31,64-95} (P1) are disjoint from P2's a-hi reads
// {32-63,96-127}; q1 stage (P3) lands after those reads. Race-free even if
// the DMA lands instantly.
// ---------------------------------------------------------------------------
template <int K, int NBN, int LDB, bool SILU>
__global__ __launch_bounds__(256, 2)
void gemm_fused(const unsigned short* __restrict__ Aall,
                const float* __restrict__ Ball,
                void* __restrict__ Cout,
                long sA, long sB, long sC) {
  extern __shared__ char smem[];
  constexpr int NT = K / 64;

  const int tid  = threadIdx.x;
  const int wave = tid >> 6;
  const int lane = tid & 63;
  const int lr   = lane & 15;
  const int lq   = lane >> 4;
  const int wid_m = wave >> 1;     // 0..1
  const int wid_n = wave & 1;      // 0..1
  const int pcol  = ((lr & 3) << 2) | (lr >> 2);   // pi(lr)

  // T1: bijective XCD swizzle (gridDim.x % 8 == 0), mb innermost (8 m-blocks
  // share one B panel -> same XCD L2).
  const int nwg = gridDim.x;
  const int bid = blockIdx.x;
  const int wg  = (bid & 7) * (nwg >> 3) + (bid >> 3);
  const int mb  = wg & 7;
  const int tmp = wg >> 3;
  const int nb  = tmp % NBN;
  const int e   = tmp / NBN;

  const unsigned short* A = Aall + (long)e * sA + (long)(mb * 128) * K;
  const float*          B = Ball + (long)e * sB;

  // ---- A staging: 16KB tile, 2 halves (q) x 2 instr; identity row map ----
  const int stl  = tid >> 3;                      // 0..31
  const int scol = ((tid & 7) ^ (stl & 7)) * 8;   // pre-swizzled src elem col

  auto stageA = [&](int bi, int q, int kt) {
    const long col = (long)kt * 64 + scol;
    char* l0 = smem + bi * 16384 + q * 4096 + wave * 1024;
    async16(A + (long)(q * 32 + stl) * K + col,       l0);          // rows q*32+0..31
    async16(A + (long)(64 + q * 32 + stl) * K + col,  l0 + 8192);   // rows 64+q*32+..
  };

  // ---- B: thread owns col-quad (quad = tid&31 -> storage rows 4q..4q+3 =
  //         4 contiguous global cols) and k-octet ko = tid>>5.
  const int quad = tid & 31;
  const int koB  = tid >> 5;                       // 0..7
  int colq;                                        // global col of st = 4*quad
  {
    const int st = 4 * quad;
    if (SILU) {
      // storage: every 32 rows = 16 gate + 16 up of the same 16 acted cols
      colq = nb * 64 + (st >> 5) * 16 + (st & 15) + (((st >> 4) & 1) ? I_ : 0);
    } else {
      colq = nb * 128 + st;
    }
  }
  const float* Bq = B + colq;

  f32x4 bv[8];
  auto LOADB = [&](int kt) {
    const long kbase = (long)kt * 64 + koB * 8;
#pragma unroll
    for (int i = 0; i < 8; ++i)
      bv[i] = *(const f32x4*)&Bq[(kbase + i) * (long)LDB];
  };
  auto WRITEB = [&](int bo) {
    char* LBw = smem + 32768 + bo * 16384;
    const int slot = koB ^ (quad & 7);             // 8 slots per 8-lane group
#pragma unroll
    for (int j = 0; j < 4; ++j) {
      bf16x8 pk;
#pragma unroll
      for (int i = 0; i < 8; ++i) pk[i] = (__bf16)bv[i][j];
      const int st = 4 * quad + j;
      *(bf16x8*)(LBw + st * 128 + slot * 16) = pk;
    }
  };

  // A fragment slot offsets (key = lr&7, conflict-free)
  const int axA0 = ((0 + lq) ^ (lr & 7)) * 16;    // k 0..31
  const int axA1 = ((4 + lq) ^ (lr & 7)) * 16;    // k 32..63

  f32x4 acc[4][4];
#pragma unroll
  for (int m = 0; m < 4; ++m)
#pragma unroll
    for (int n = 0; n < 4; ++n) acc[m][n] = (f32x4)0.0f;

  // B-frag read helper: nf in 0..3, ks in 0..1
  auto readB = [&](const char* LB, int nf, int ks) -> bf16x8 {
    const int st = wid_n * 64 + nf * 16 + pcol;
    const int sl = ((ks * 4 + lq) ^ ((st >> 2) & 7)) * 16;
    return *(const bf16x8*)(LB + st * 128 + sl);
  };

  // ---------------- prologue --------------------------------------------
  const int t1p = (NT > 1) ? 1 : 0;
  LOADB(0);                    // 8: B(0)
  stageA(0, 0, 0);             // 2
  stageA(0, 1, 0);             // 2
  SB0();
  WAITVM(4); SB0();            // B(0) regs ready (leaves A(0) 4)
  WRITEB(0);
  WAITLGKM(); SB0();           // publish B(0); bv free (WAR)
  stageA(1, 0, t1p); SB0();    // 2  q0(1)
  LOADB(t1p); SB0();           // 8  B(1)
  stageA(1, 1, t1p); SB0();    // 2  q1(1)
  WAITVM(12); SB0();           // retire A(0); leaves [q0(1)2, B(1)8, q1(1)2]
  BAR();

#pragma unroll 1
  for (int t = 0; t < NT; ++t) {
    const int cur = t & 1;
    const int bo  = cur ^ 1;
    const char* LA = smem + cur * 16384;
    const char* LB = smem + 32768 + cur * 16384;
    const int t2v = (t + 2 < NT) ? t + 2 : NT - 1;

    bf16x8 aLo[2][2], aHi[2][2], bLo[2][2], bHi[2][2];

    // ---- P0: read aLo(mf0-1) + bLo(nf0-1); no VMEM ----------------------
#pragma unroll
    for (int mf = 0; mf < 2; ++mf) {
      const int st = wid_m * 64 + mf * 16 + lr;
      aLo[mf][0] = *(const bf16x8*)(LA + st * 128 + axA0);
      aLo[mf][1] = *(const bf16x8*)(LA + st * 128 + axA1);
    }
#pragma unroll
    for (int nf = 0; nf < 2; ++nf) {
      bLo[nf][0] = readB(LB, nf, 0);
      bLo[nf][1] = readB(LB, nf, 1);
    }
    SB0();
    BAR();
    WAITLGKM(); SB0();
    __builtin_amdgcn_s_setprio(1);
#pragma unroll
    for (int mf = 0; mf < 2; ++mf)
#pragma unroll
      for (int nf = 0; nf < 2; ++nf) {
        acc[mf][nf] = __builtin_amdgcn_mfma_f32_16x16x32_bf16(aLo[mf][0], bLo[nf][0], acc[mf][nf], 0, 0, 0);
        acc[mf][nf] = __builtin_amdgcn_mfma_f32_16x16x32_bf16(aLo[mf][1], bLo[nf][1], acc[mf][nf], 0, 0, 0);
      }
    __builtin_amdgcn_s_setprio(0);
    BAR();

    // ---- P1: read bHi(nf2-3); issue A q0(t+2) [rows 0-31,64-95] ---------
#pragma unroll
    for (int nf = 0; nf < 2; ++nf) {
      bHi[nf][0] = readB(LB, 2 + nf, 0);
      bHi[nf][1] = readB(LB, 2 + nf, 1);
    }
    stageA(cur, 0, t2v);
    SB0();
    BAR();
    WAITLGKM(); SB0();
    __builtin_amdgcn_s_setprio(1);
#pragma unroll
    for (int mf = 0; mf < 2; ++mf)
#pragma unroll
      for (int nf = 0; nf < 2; ++nf) {
        acc[mf][2 + nf] = __builtin_amdgcn_mfma_f32_16x16x32_bf16(aLo[mf][0], bHi[nf][0], acc[mf][2 + nf], 0, 0, 0);
        acc[mf][2 + nf] = __builtin_amdgcn_mfma_f32_16x16x32_bf16(aLo[mf][1], bHi[nf][1], acc[mf][2 + nf], 0, 0, 0);
      }
    __builtin_amdgcn_s_setprio(0);
    BAR();

    // ---- P2: read aHi(mf2-3) [rows 32-63,96-127]; vmcnt(4) -> WRITEB
    //          B(t+1); lgkm; LOADB B(t+2) ---------------------------------
#pragma unroll
    for (int mf = 0; mf < 2; ++mf) {
      const int st = wid_m * 64 + 32 + mf * 16 + lr;
      aHi[mf][0] = *(const bf16x8*)(LA + st * 128 + axA0);
      aHi[mf][1] = *(const bf16x8*)(LA + st * 128 + axA1);
    }
    SB0();
    WAITVM(4); SB0();          // retires B(t+1) (+q0(t+1) already old)
    WRITEB(bo);
    WAITLGKM(); SB0();         // aHi reads + B writes drained; bv free
    LOADB(t2v);                // 8 f4 B(t+2)
    SB0();
    BAR();
    __builtin_amdgcn_s_setprio(1);
#pragma unroll
    for (int mf = 0; mf < 2; ++mf)
#pragma unroll
      for (int nf = 0; nf < 2; ++nf) {
        acc[2 + mf][2 + nf] = __builtin_amdgcn_mfma_f32_16x16x32_bf16(aHi[mf][0], bHi[nf][0], acc[2 + mf][2 + nf], 0, 0, 0);
        acc[2 + mf][2 + nf] = __builtin_amdgcn_mfma_f32_16x16x32_bf16(aHi[mf][1], bHi[nf][1], acc[2 + mf][2 + nf], 0, 0, 0);
      }
    __builtin_amdgcn_s_setprio(0);
    BAR();

    // ---- P3: issue A q1(t+2) [rows 32-63,96-127]; vmcnt(12) -------------
    stageA(cur, 1, t2v);
    SB0();
    WAITVM(12); SB0();         // retires q1(t+1)
    BAR();
    __builtin_amdgcn_s_setprio(1);
#pragma unroll
    for (int mf = 0; mf < 2; ++mf)
#pragma unroll
      for (int nf = 0; nf < 2; ++nf) {
        acc[2 + mf][nf] = __builtin_amdgcn_mfma_f32_16x16x32_bf16(aHi[mf][0], bLo[nf][0], acc[2 + mf][nf], 0, 0, 0);
        acc[2 + mf][nf] = __builtin_amdgcn_mfma_f32_16x16x32_bf16(aHi[mf][1], bLo[nf][1], acc[2 + mf][nf], 0, 0, 0);
      }
    __builtin_amdgcn_s_setprio(0);
    BAR();
  }

  WAITVM(0);                   // trailing clamped loads must not outlive LDS

  // -------- epilogue (C/D: col=lane&15, row=(lane>>4)*4+r; col -> pi) ----
  if (SILU) {
    unsigned short* Cc = (unsigned short*)Cout + (long)e * sC;
#pragma unroll
    for (int mf = 0; mf < 4; ++mf)
#pragma unroll
      for (int p = 0; p < 2; ++p)
#pragma unroll
        for (int rr = 0; rr < 4; ++rr) {
          const int row = mb * 128 + wid_m * 64 + mf * 16 + lq * 4 + rr;
          const int col = nb * 64 + wid_n * 32 + p * 16 + pcol;
          const float g = acc[mf][p * 2][rr];
          const float u = acc[mf][p * 2 + 1][rr];
          Cc[(long)row * I_ + col] = f2bf(u * (g / (1.0f + __expf(-g))));
        }
  } else {
    float* Cc = (float*)Cout + (long)e * sC;
#pragma unroll
    for (int mf = 0; mf < 4; ++mf)
#pragma unroll
      for (int nf = 0; nf < 4; ++nf)
#pragma unroll
        for (int rr = 0; rr < 4; ++rr) {
          const int row = mb * 128 + wid_m * 64 + mf * 16 + lq * 4 + rr;
          const int col = nb * 128 + wid_n * 64 + nf * 16 + pcol;
          Cc[(long)row * H_ + col] = acc[mf][nf][rr];
        }
  }
}

// ---------------------------------------------------------------------------
extern "C" void kernel_launch(void* const* d_in, const int* in_sizes, int n_in,
                              void* d_out, int out_size, void* d_ws, size_t ws_size,
                              hipStream_t stream) {
  const float* hs = (const float*)d_in[0];   // (8192, 2048)
  const float* w1 = (const float*)d_in[1];   // (8, 2048, 8192)
  const float* w2 = (const float*)d_in[2];   // (8, 4096, 2048)
  float* out = (float*)d_out;                // (8192, 2048) fp32
  char* ws = (char*)d_ws;

  const long HB_B  = (long)T_ * H_ * 2;      // 32 MiB hidden bf16
  const long ACT_B = (long)T_ * I_ * 2;      // 64 MiB acted bf16
  if (ws_size < (size_t)(HB_B + ACT_B)) return;

  unsigned short* hiddenB = (unsigned short*)(ws);
  unsigned short* acted   = (unsigned short*)(ws + HB_B);

  hipLaunchKernelGGL(convert_bf16, dim3(2048), dim3(256), 0, stream,
                     hs, hiddenB, (long)T_ * H_);

  // gemm1+SiLU: A=hiddenB (TPE,H), B=W1 (H,2I) fp32 -> acted bf16
  // grid: 8 mb x 64 nb x 8 e = 4096
  hipLaunchKernelGGL((gemm_fused<H_, 64, 2 * I_, true>),
                     dim3(4096), dim3(256), 65536, stream,
                     hiddenB, w1, acted,
                     (long)TPE * H_, (long)H_ * 2 * I_, (long)TPE * I_);

  // gemm2: A=acted (TPE,I), B=W2 (I,H) fp32 -> out fp32
  // grid: 8 mb x 16 nb x 8 e = 1024
  hipLaunchKernelGGL((gemm_fused<I_, 16, H_, false>),
                     dim3(1024), dim3(256), 65536, stream,
                     acted, w2, out,
                     (long)TPE * I_, (long)I_ * H_, (long)TPE * H_);
}